// Round 1
// baseline (771.903 us; speedup 1.0000x reference)
//
#include <hip/hip_runtime.h>
#include <hip/hip_bf16.h>
#include <stdint.h>

#define D_DIM 12544
#define NROIS 8192
#define NCOLS 168        // valid output cols: 32+124+3+7+2
#define NCOLS_PAD 176    // 11 tiles of 16
#define NT 11
#define SPLIT 4
#define KSPLIT (D_DIM / SPLIT)   // 3136
#define KITERS (KSPLIT / 32)     // 98

typedef __attribute__((ext_vector_type(8))) short short8;   // 8 bf16 = 4 VGPRs (MFMA A/B frag)
typedef __attribute__((ext_vector_type(4))) float floatx4;  // MFMA C/D frag

__device__ __forceinline__ uint32_t pk_bf16(float a, float b) {
    // round-to-nearest-even fp32 -> bf16, packed pair
    uint32_t ua = __float_as_uint(a);
    uint32_t ub = __float_as_uint(b);
    ua = (ua + 0x7FFFu + ((ua >> 16) & 1u)) >> 16;
    ub = (ub + 0x7FFFu + ((ub >> 16) & 1u)) >> 16;
    return ua | (ub << 16);
}

// ---------------- pack W (5 heads) -> Wp[NCOLS_PAD][D_DIM] bf16, K-major ----
__global__ void pack_w(const float* __restrict__ Wc, const float* __restrict__ Wr,
                       const float* __restrict__ Wf, const float* __restrict__ Wco,
                       const float* __restrict__ Wm, uint16_t* __restrict__ Wp) {
    int c = blockIdx.y * 16 + threadIdx.x;   // 0..175
    int k = blockIdx.x * 16 + threadIdx.y;   // 0..12543
    float v = 0.f;
    if (c < 32)       v = Wc[(size_t)k * 32  + c];
    else if (c < 156) v = Wr[(size_t)k * 124 + (c - 32)];
    else if (c < 159) v = Wf[(size_t)k * 3   + (c - 156)];
    else if (c < 166) v = Wco[(size_t)k * 7  + (c - 159)];
    else if (c < 168) v = Wm[(size_t)k * 2   + (c - 166)];
    uint32_t u = __float_as_uint(v);
    Wp[(size_t)c * D_DIM + k] = (uint16_t)((u + 0x7FFFu + ((u >> 16) & 1u)) >> 16);
}

// ---------------- split-K GEMM: parts[split][row][NCOLS] ---------------------
__global__ __launch_bounds__(256) void gemm_split(const float* __restrict__ X,
                                                  const uint16_t* __restrict__ Wp,
                                                  float* __restrict__ parts) {
    int b    = blockIdx.x;          // 0..511
    int wave = threadIdx.x >> 6;    // 0..3
    int lane = threadIdx.x & 63;
    // XCD swizzle: blocks land on XCD ~ b&7 (round-robin). Pin each K-split's
    // W slice (1.2 MB bf16) to 2 XCDs so it stays L2-resident.
    int xcd   = b & 7;
    int split = xcd >> 1;                         // 0..3
    int idx   = ((b >> 3) << 1) | (b & 1);        // 0..127
    int rt    = idx * 4 + wave;                   // 0..511 row tile (16 rows)
    int row0  = rt * 16;
    int kbase = split * KSPLIT;

    int n    = lane & 15;   // row-in-tile (B frag n) / out-col-in-tile (A frag m)
    int quad = lane >> 4;

    const float*    xp = X  + (size_t)(row0 + n) * D_DIM + kbase + quad * 8;
    const uint16_t* wp = Wp + (size_t)n          * D_DIM + kbase + quad * 8;

    floatx4 acc[NT];
#pragma unroll
    for (int t = 0; t < NT; ++t) acc[t] = (floatx4)0.f;

    for (int it = 0; it < KITERS; ++it) {
        float4 xa = *(const float4*)xp;
        float4 xb = *(const float4*)(xp + 4);
        xp += 32;

        short8 wf[NT];
#pragma unroll
        for (int t = 0; t < NT; ++t)
            wf[t] = *(const short8*)(wp + (size_t)t * (16 * D_DIM));
        wp += 32;

        union { uint32_t u[4]; short8 s; } xc;
        xc.u[0] = pk_bf16(xa.x, xa.y);
        xc.u[1] = pk_bf16(xa.z, xa.w);
        xc.u[2] = pk_bf16(xb.x, xb.y);
        xc.u[3] = pk_bf16(xb.z, xb.w);
        short8 xf = xc.s;

#pragma unroll
        for (int t = 0; t < NT; ++t)
            acc[t] = __builtin_amdgcn_mfma_f32_16x16x32_bf16(wf[t], xf, acc[t], 0, 0, 0);

        // loose phase-lock of the 4 waves (shared W stream -> L1 hits);
        // raw barrier: no s_waitcnt drain, perf-only.
        if ((it & 7) == 7) __builtin_amdgcn_s_barrier();
    }

    // D layout (16x16x32): col(n)=lane&15, row(m)=quad*4+reg. Here n = X row,
    // m = output col. Store float4 of 4 consecutive cols.
    float* pb = parts + ((size_t)split * NROIS + row0 + n) * NCOLS;
#pragma unroll
    for (int t = 0; t < NT; ++t) {
        int col0 = t * 16 + quad * 4;
        if (col0 < NCOLS) *(floatx4*)(pb + col0) = acc[t];
    }
}

// ---------------- reduce partials + bias, scatter to 5 heads ----------------
__global__ void reduce_out(const float* __restrict__ parts,
                           const float* __restrict__ bc, const float* __restrict__ br,
                           const float* __restrict__ bf, const float* __restrict__ bco,
                           const float* __restrict__ bm, float* __restrict__ out) {
    int r = blockIdx.x;
    int c = threadIdx.x;
    if (c >= NCOLS) return;
    const size_t S = (size_t)NROIS * NCOLS;
    size_t off = (size_t)r * NCOLS + c;
    float v = parts[off] + parts[off + S] + parts[off + 2 * S] + parts[off + 3 * S];
    float bias; size_t oidx;
    if (c < 32)       { bias = bc[c];        oidx = (size_t)r * 32  + c; }
    else if (c < 156) { bias = br[c - 32];   oidx = 262144u  + (size_t)r * 124 + (c - 32); }
    else if (c < 159) { bias = bf[c - 156];  oidx = 1277952u + (size_t)r * 3   + (c - 156); }
    else if (c < 166) { bias = bco[c - 159]; oidx = 1302528u + (size_t)r * 7   + (c - 159); }
    else              { bias = bm[c - 166];  oidx = 1359872u + (size_t)r * 2   + (c - 166); }
    out[oidx] = v + bias;
}

extern "C" void kernel_launch(void* const* d_in, const int* in_sizes, int n_in,
                              void* d_out, int out_size, void* d_ws, size_t ws_size,
                              hipStream_t stream) {
    const float* X   = (const float*)d_in[0];
    const float* Wc  = (const float*)d_in[1];
    const float* bc  = (const float*)d_in[2];
    const float* Wr  = (const float*)d_in[3];
    const float* br  = (const float*)d_in[4];
    const float* Wf  = (const float*)d_in[5];
    const float* bfa = (const float*)d_in[6];
    const float* Wco = (const float*)d_in[7];
    const float* bco = (const float*)d_in[8];
    const float* Wm  = (const float*)d_in[9];
    const float* bm  = (const float*)d_in[10];

    uint16_t* Wp = (uint16_t*)d_ws;                                  // 4,415,488 B
    float* parts = (float*)((char*)d_ws + (size_t)NCOLS_PAD * D_DIM * 2); // 22,020,096 B
    float* out   = (float*)d_out;

    pack_w<<<dim3(D_DIM / 16, NCOLS_PAD / 16), dim3(16, 16), 0, stream>>>(Wc, Wr, Wf, Wco, Wm, Wp);
    gemm_split<<<512, 256, 0, stream>>>(X, Wp, parts);
    reduce_out<<<NROIS, 192, 0, stream>>>(parts, bc, br, bfa, bco, bm, out);
}

// Round 2
// 754.980 us; speedup vs baseline: 1.0224x; 1.0224x over previous
//
#include <hip/hip_runtime.h>
#include <hip/hip_bf16.h>
#include <stdint.h>

#define D_DIM 12544
#define NROIS 8192
#define NCOLS 168        // valid output cols: 32+124+3+7+2
#define NCOLS_PAD 176    // 11 tiles of 16
#define NT 11
#define SPLIT 4
#define KSPLIT (D_DIM / SPLIT)   // 3136
#define KITERS (KSPLIT / 32)     // 98

typedef __attribute__((ext_vector_type(8))) short short8;   // 8 bf16 = 4 VGPRs (MFMA A/B frag)
typedef __attribute__((ext_vector_type(4))) float floatx4;  // MFMA C/D frag

__device__ __forceinline__ uint32_t pk_bf16(float a, float b) {
    // round-to-nearest-even fp32 -> bf16, packed pair
    uint32_t ua = __float_as_uint(a);
    uint32_t ub = __float_as_uint(b);
    ua = (ua + 0x7FFFu + ((ua >> 16) & 1u)) >> 16;
    ub = (ub + 0x7FFFu + ((ub >> 16) & 1u)) >> 16;
    return ua | (ub << 16);
}

// ---------------- pack W (5 heads) -> Wp[NCOLS_PAD][D_DIM] bf16, K-major ----
// x = k (64 lanes -> 128B contiguous bf16 writes), y = c. Reads are strided
// but the whole W set is 8.4 MB -> L2-resident across blocks.
__global__ __launch_bounds__(256) void pack_w(
        const float* __restrict__ Wc, const float* __restrict__ Wr,
        const float* __restrict__ Wf, const float* __restrict__ Wco,
        const float* __restrict__ Wm, uint16_t* __restrict__ Wp) {
    int k = blockIdx.x * 64 + threadIdx.x;   // 0..12543 (196 blocks)
    int c = blockIdx.y * 4  + threadIdx.y;   // 0..175   (44 blocks)
    float v = 0.f;
    if (c < 32)       v = Wc[(size_t)k * 32  + c];
    else if (c < 156) v = Wr[(size_t)k * 124 + (c - 32)];
    else if (c < 159) v = Wf[(size_t)k * 3   + (c - 156)];
    else if (c < 166) v = Wco[(size_t)k * 7  + (c - 159)];
    else if (c < 168) v = Wm[(size_t)k * 2   + (c - 166)];
    uint32_t u = __float_as_uint(v);
    Wp[(size_t)c * D_DIM + k] = (uint16_t)((u + 0x7FFFu + ((u >> 16) & 1u)) >> 16);
}

// ---------------- split-K GEMM: parts[split][row][NCOLS] ---------------------
// Software-pipelined: issue iter i+1 loads before iter i MFMAs so each wave
// keeps ~2 iterations (26 KB) of loads in flight -> BW-bound, not latency.
__global__ __launch_bounds__(256) void gemm_split(const float* __restrict__ X,
                                                  const uint16_t* __restrict__ Wp,
                                                  float* __restrict__ parts) {
    int b    = blockIdx.x;          // 0..511
    int wave = threadIdx.x >> 6;    // 0..3
    int lane = threadIdx.x & 63;
    // XCD swizzle (blocks round-robin XCDs): pin each K-split's 1.1 MB W slice
    // to 2 XCDs so it stays L2-resident.
    int xcd   = b & 7;
    int split = xcd >> 1;                         // 0..3
    int idx   = ((b >> 3) << 1) | (b & 1);        // 0..127
    int rt    = idx * 4 + wave;                   // 0..511 row tile (16 rows)
    int row0  = rt * 16;
    int kbase = split * KSPLIT;

    int n    = lane & 15;   // X row in tile (B frag) / W out-col in tile (A frag)
    int quad = lane >> 4;

    const float*    xp = X  + (size_t)(row0 + n) * D_DIM + kbase + quad * 8;
    const uint16_t* wp = Wp + (size_t)n          * D_DIM + kbase + quad * 8;

    floatx4 acc[NT];
#pragma unroll
    for (int t = 0; t < NT; ++t) acc[t] = (floatx4)0.f;

    // prologue: iter-0 loads
    float4 xa = *(const float4*)xp;
    float4 xb = *(const float4*)(xp + 4);
    short8 wf[NT];
#pragma unroll
    for (int t = 0; t < NT; ++t)
        wf[t] = *(const short8*)(wp + (size_t)t * (16 * D_DIM));

#pragma unroll 2
    for (int it = 0; it < KITERS; ++it) {
        // next-iter addresses (last iter: reload current addr, value unused)
        const float*    xq = xp + 32;
        const uint16_t* wq = wp + 32;
        if (it == KITERS - 1) { xq = xp; wq = wp; }

        // issue next-iter loads FIRST (deep in flight while we compute)
        float4 xa_n = *(const float4*)xq;
        float4 xb_n = *(const float4*)(xq + 4);
        short8 wf_n[NT];
#pragma unroll
        for (int t = 0; t < NT; ++t)
            wf_n[t] = *(const short8*)(wq + (size_t)t * (16 * D_DIM));

        // compute on current regs
        union { uint32_t u[4]; short8 s; } xc;
        xc.u[0] = pk_bf16(xa.x, xa.y);
        xc.u[1] = pk_bf16(xa.z, xa.w);
        xc.u[2] = pk_bf16(xb.x, xb.y);
        xc.u[3] = pk_bf16(xb.z, xb.w);
        short8 xf = xc.s;
#pragma unroll
        for (int t = 0; t < NT; ++t)
            acc[t] = __builtin_amdgcn_mfma_f32_16x16x32_bf16(wf[t], xf, acc[t], 0, 0, 0);

        // rotate (renamed away by unroll-2)
        xa = xa_n; xb = xb_n;
#pragma unroll
        for (int t = 0; t < NT; ++t) wf[t] = wf_n[t];
        xp = xq; wp = wq;
    }

    // D layout (16x16x32): col(n)=lane&15 -> X row, row(m)=quad*4+reg -> out col.
    float* pb = parts + ((size_t)split * NROIS + row0 + n) * NCOLS;
#pragma unroll
    for (int t = 0; t < NT; ++t) {
        int col0 = t * 16 + quad * 4;
        if (col0 < NCOLS) *(floatx4*)(pb + col0) = acc[t];
    }
}

// ---------------- reduce partials + bias, scatter to 5 heads ----------------
__global__ void reduce_out(const float* __restrict__ parts,
                           const float* __restrict__ bc, const float* __restrict__ br,
                           const float* __restrict__ bf, const float* __restrict__ bco,
                           const float* __restrict__ bm, float* __restrict__ out) {
    int r = blockIdx.x;
    int c = threadIdx.x;
    if (c >= NCOLS) return;
    const size_t S = (size_t)NROIS * NCOLS;
    size_t off = (size_t)r * NCOLS + c;
    float v = parts[off] + parts[off + S] + parts[off + 2 * S] + parts[off + 3 * S];
    float bias; size_t oidx;
    if (c < 32)       { bias = bc[c];        oidx = (size_t)r * 32  + c; }
    else if (c < 156) { bias = br[c - 32];   oidx = 262144u  + (size_t)r * 124 + (c - 32); }
    else if (c < 159) { bias = bf[c - 156];  oidx = 1277952u + (size_t)r * 3   + (c - 156); }
    else if (c < 166) { bias = bco[c - 159]; oidx = 1302528u + (size_t)r * 7   + (c - 159); }
    else              { bias = bm[c - 166];  oidx = 1359872u + (size_t)r * 2   + (c - 166); }
    out[oidx] = v + bias;
}

extern "C" void kernel_launch(void* const* d_in, const int* in_sizes, int n_in,
                              void* d_out, int out_size, void* d_ws, size_t ws_size,
                              hipStream_t stream) {
    const float* X   = (const float*)d_in[0];
    const float* Wc  = (const float*)d_in[1];
    const float* bc  = (const float*)d_in[2];
    const float* Wr  = (const float*)d_in[3];
    const float* br  = (const float*)d_in[4];
    const float* Wf  = (const float*)d_in[5];
    const float* bfa = (const float*)d_in[6];
    const float* Wco = (const float*)d_in[7];
    const float* bco = (const float*)d_in[8];
    const float* Wm  = (const float*)d_in[9];
    const float* bm  = (const float*)d_in[10];

    uint16_t* Wp = (uint16_t*)d_ws;                                       // 4,415,488 B
    float* parts = (float*)((char*)d_ws + (size_t)NCOLS_PAD * D_DIM * 2); // 22,020,096 B
    float* out   = (float*)d_out;

    pack_w<<<dim3(D_DIM / 64, NCOLS_PAD / 4), dim3(64, 4), 0, stream>>>(Wc, Wr, Wf, Wco, Wm, Wp);
    gemm_split<<<512, 256, 0, stream>>>(X, Wp, parts);
    reduce_out<<<NROIS, 192, 0, stream>>>(parts, bc, br, bfa, bco, bm, out);
}

// Round 3
// 609.250 us; speedup vs baseline: 1.2670x; 1.2392x over previous
//
#include <hip/hip_runtime.h>
#include <hip/hip_bf16.h>
#include <stdint.h>

#define D_DIM 12544
#define NROIS 8192
#define NCOLS 168        // valid output cols: 32+124+3+7+2
#define NCPAD 176        // padded cols in Wp (cols 168..175 are zeros)
#define NT 11
#define SPLIT 8
#define KSPLIT (D_DIM / SPLIT)   // 1568
#define BK 32
#define KITERS (KSPLIT / BK)     // 49
#define BM 64

// LDS layout (bytes): X tile 64 rows x 32 bf16 (64B) padded to 72B -> 2-way banks
//                     W tile 192 cols x 32 bf16 (64B) padded to 80B -> 2-way banks
#define XROW_B 72
#define WCOL_B 80
#define WL_COLS 192
#define XL_BYTES (BM * XROW_B)            // 4608
#define WL_BYTES (WL_COLS * WCOL_B)       // 15360
#define BUF_BYTES (XL_BYTES + WL_BYTES)   // 19968

typedef __attribute__((ext_vector_type(8))) short short8;   // 8 bf16 (MFMA A/B frag)
typedef __attribute__((ext_vector_type(4))) float floatx4;  // MFMA C/D frag

__device__ __forceinline__ uint32_t pk_bf16(float a, float b) {
    uint32_t ua = __float_as_uint(a);
    uint32_t ub = __float_as_uint(b);
    ua = (ua + 0x7FFFu + ((ua >> 16) & 1u)) >> 16;
    ub = (ub + 0x7FFFu + ((ub >> 16) & 1u)) >> 16;
    return ua | (ub << 16);
}

// ---------------- pack W (5 heads) -> Wp[NCPAD][D_DIM] bf16, K-major --------
// LDS-transpose tile (64k x 32c): reads coalesced along c, writes coalesced
// along k (128 B per col).
__global__ __launch_bounds__(256) void pack_w(
        const float* __restrict__ Wc, const float* __restrict__ Wr,
        const float* __restrict__ Wf, const float* __restrict__ Wco,
        const float* __restrict__ Wm, uint16_t* __restrict__ Wp) {
    __shared__ float tile[64][33];
    int k0 = blockIdx.x * 64;
    int c0 = blockIdx.y * 32;
    int t  = threadIdx.x;

    int rc = t & 31;        // read col within tile
    int rk = t >> 5;        // 0..7
#pragma unroll
    for (int rr = 0; rr < 8; ++rr) {
        int k = rr * 8 + rk;
        int kk = k0 + k;
        int c = c0 + rc;
        float v = 0.f;
        if (c < 32)       v = Wc[(size_t)kk * 32  + c];
        else if (c < 156) v = Wr[(size_t)kk * 124 + (c - 32)];
        else if (c < 159) v = Wf[(size_t)kk * 3   + (c - 156)];
        else if (c < 166) v = Wco[(size_t)kk * 7  + (c - 159)];
        else if (c < 168) v = Wm[(size_t)kk * 2   + (c - 166)];
        tile[k][rc] = v;
    }
    __syncthreads();

    int wc = t >> 3;        // 0..31 write col
    int wk = t & 7;         // k-chunk (8 bf16 = 16 B)
    int c  = c0 + wc;
    if (c < NCPAD) {
        uint32_t o[4];
#pragma unroll
        for (int j = 0; j < 4; ++j)
            o[j] = pk_bf16(tile[wk * 8 + 2 * j][wc], tile[wk * 8 + 2 * j + 1][wc]);
        uint4 v = make_uint4(o[0], o[1], o[2], o[3]);
        *(uint4*)(Wp + (size_t)c * D_DIM + k0 + wk * 8) = v;
    }
}

// ---------------- split-K GEMM, LDS-staged, parts bf16 ----------------------
__global__ __launch_bounds__(256) void gemm_split(const float* __restrict__ X,
                                                  const uint16_t* __restrict__ Wp,
                                                  uint16_t* __restrict__ parts) {
    __shared__ __attribute__((aligned(16))) char lds[2 * BUF_BYTES];

    int b     = blockIdx.x;       // 0..1023
    int split = b & 7;            // one split per XCD (if round-robin): W slice 552 KB L2-resident
    int rb    = b >> 3;           // 0..127
    int row0  = rb * BM;
    int kbase = split * KSPLIT;

    int t    = threadIdx.x;
    int wave = t >> 6;
    int lane = t & 63;

    // ---- staging roles ----
    int sx_row = t >> 2;          // 0..63
    int sx_kc  = t & 3;           // 16B chunk (8 fp32 -> 8 bf16)
    const float* xg = X + (size_t)(row0 + sx_row) * D_DIM + kbase + sx_kc * 8;

    int sw_col = t >> 2;          // 0..63, rounds add 64/128
    int sw_ch  = t & 3;           // 16B chunk within col's 64B k-row
    int c0g = sw_col       < NCPAD ? sw_col       : NCPAD - 1;
    int c1g = sw_col + 64  < NCPAD ? sw_col + 64  : NCPAD - 1;
    int c2g = sw_col + 128 < NCPAD ? sw_col + 128 : NCPAD - 1;
    const uint16_t* wg0 = Wp + (size_t)c0g * D_DIM + kbase + sw_ch * 8;
    const uint16_t* wg1 = Wp + (size_t)c1g * D_DIM + kbase + sw_ch * 8;
    const uint16_t* wg2 = Wp + (size_t)c2g * D_DIM + kbase + sw_ch * 8;

    // staging LDS offsets (lane-distinct, 2-way banks max)
    int x_st = sx_row * XROW_B + sx_kc * 16;
    int w_st0 = XL_BYTES + (sw_col)       * WCOL_B + sw_ch * 16;
    int w_st1 = XL_BYTES + (sw_col + 64)  * WCOL_B + sw_ch * 16;
    int w_st2 = XL_BYTES + (sw_col + 128) * WCOL_B + sw_ch * 16;

    // ---- frag roles ----
    int n    = lane & 15;         // X row within wave tile / W col within tile
    int quad = lane >> 4;         // k-chunk
    int xf_off = (wave * 16 + n) * XROW_B + quad * 16;
    int wf_off = XL_BYTES + n * WCOL_B + quad * 16;   // + tt*16*WCOL_B

    floatx4 acc[NT];
#pragma unroll
    for (int tt = 0; tt < NT; ++tt) acc[tt] = (floatx4)0.f;

    // ---- prologue: load + stage iter 0 into buf0 ----
    float4 px0 = *(const float4*)xg;
    float4 px1 = *(const float4*)(xg + 4);
    xg += BK;
    short8 pw0 = *(const short8*)wg0; wg0 += BK;
    short8 pw1 = *(const short8*)wg1; wg1 += BK;
    short8 pw2 = *(const short8*)wg2; wg2 += BK;
    {
        union { uint32_t u[4]; short8 s; } p;
        p.u[0] = pk_bf16(px0.x, px0.y); p.u[1] = pk_bf16(px0.z, px0.w);
        p.u[2] = pk_bf16(px1.x, px1.y); p.u[3] = pk_bf16(px1.z, px1.w);
        *(short8*)(lds + x_st) = p.s;
        *(short8*)(lds + w_st0) = pw0;
        *(short8*)(lds + w_st1) = pw1;
        *(short8*)(lds + w_st2) = pw2;
    }
    int cur = 0;

    for (int it = 0; it < KITERS; ++it) {
        __syncthreads();   // staged buf[cur] visible; prev iter's reads of buf[cur^1] done

        // issue next-iter global loads (in flight during frag+MFMA phase)
        float4 nx0, nx1; short8 nw0, nw1, nw2;
        bool more = (it + 1 < KITERS);
        if (more) {
            nx0 = *(const float4*)xg;
            nx1 = *(const float4*)(xg + 4);
            xg += BK;
            nw0 = *(const short8*)wg0; wg0 += BK;
            nw1 = *(const short8*)wg1; wg1 += BK;
            nw2 = *(const short8*)wg2; wg2 += BK;
        }

        // fragments from buf[cur] + MFMA
        const char* cb = lds + cur * BUF_BYTES;
        short8 xf = *(const short8*)(cb + xf_off);
#pragma unroll
        for (int tt = 0; tt < NT; ++tt) {
            short8 wf = *(const short8*)(cb + wf_off + tt * (16 * WCOL_B));
            acc[tt] = __builtin_amdgcn_mfma_f32_16x16x32_bf16(wf, xf, acc[tt], 0, 0, 0);
        }

        // stage next iter into the other buffer (no barrier needed: its readers
        // finished before the barrier at top of this iter)
        if (more) {
            char* nb = lds + (cur ^ 1) * BUF_BYTES;
            union { uint32_t u[4]; short8 s; } p;
            p.u[0] = pk_bf16(nx0.x, nx0.y); p.u[1] = pk_bf16(nx0.z, nx0.w);
            p.u[2] = pk_bf16(nx1.x, nx1.y); p.u[3] = pk_bf16(nx1.z, nx1.w);
            *(short8*)(nb + x_st) = p.s;
            *(short8*)(nb + w_st0) = nw0;
            *(short8*)(nb + w_st1) = nw1;
            *(short8*)(nb + w_st2) = nw2;
            cur ^= 1;
        }
    }

    // ---- epilogue: D layout col(n)=X row, out-col = quad*4+reg (+16*tt) ----
    uint16_t* pb = parts + ((size_t)split * NROIS + row0 + wave * 16 + n) * NCOLS;
#pragma unroll
    for (int tt = 0; tt < NT; ++tt) {
        int col0 = tt * 16 + quad * 4;
        if (col0 + 3 < NCOLS) {
            uint32_t lo = pk_bf16(acc[tt].x, acc[tt].y);
            uint32_t hi = pk_bf16(acc[tt].z, acc[tt].w);
            uint2 v = make_uint2(lo, hi);
            *(uint2*)(pb + col0) = v;
        }
    }
}

// ---------------- reduce partials (bf16) + bias, scatter to 5 heads ---------
__global__ void reduce_out(const uint16_t* __restrict__ parts,
                           const float* __restrict__ bc, const float* __restrict__ br,
                           const float* __restrict__ bf, const float* __restrict__ bco,
                           const float* __restrict__ bm, float* __restrict__ out) {
    int r = blockIdx.x;
    int c = threadIdx.x;
    if (c >= NCOLS) return;
    const size_t S = (size_t)NROIS * NCOLS;
    size_t off = (size_t)r * NCOLS + c;
    float v = 0.f;
#pragma unroll
    for (int s = 0; s < SPLIT; ++s)
        v += __uint_as_float((uint32_t)parts[off + (size_t)s * S] << 16);
    float bias; size_t oidx;
    if (c < 32)       { bias = bc[c];        oidx = (size_t)r * 32  + c; }
    else if (c < 156) { bias = br[c - 32];   oidx = 262144u  + (size_t)r * 124 + (c - 32); }
    else if (c < 159) { bias = bf[c - 156];  oidx = 1277952u + (size_t)r * 3   + (c - 156); }
    else if (c < 166) { bias = bco[c - 159]; oidx = 1302528u + (size_t)r * 7   + (c - 159); }
    else              { bias = bm[c - 166];  oidx = 1359872u + (size_t)r * 2   + (c - 166); }
    out[oidx] = v + bias;
}

extern "C" void kernel_launch(void* const* d_in, const int* in_sizes, int n_in,
                              void* d_out, int out_size, void* d_ws, size_t ws_size,
                              hipStream_t stream) {
    const float* X   = (const float*)d_in[0];
    const float* Wc  = (const float*)d_in[1];
    const float* bc  = (const float*)d_in[2];
    const float* Wr  = (const float*)d_in[3];
    const float* br  = (const float*)d_in[4];
    const float* Wf  = (const float*)d_in[5];
    const float* bfa = (const float*)d_in[6];
    const float* Wco = (const float*)d_in[7];
    const float* bco = (const float*)d_in[8];
    const float* Wm  = (const float*)d_in[9];
    const float* bm  = (const float*)d_in[10];

    uint16_t* Wp    = (uint16_t*)d_ws;                                   // 4,415,488 B
    uint16_t* parts = (uint16_t*)((char*)d_ws + (size_t)NCPAD * D_DIM * 2); // 22,020,096 B (bf16)
    float* out = (float*)d_out;

    pack_w<<<dim3(D_DIM / 64, 6), 256, 0, stream>>>(Wc, Wr, Wf, Wco, Wm, Wp);
    gemm_split<<<1024, 256, 0, stream>>>(X, Wp, parts);
    reduce_out<<<NROIS, 192, 0, stream>>>(parts, bc, br, bfa, bco, bm, out);
}